// Round 8
// baseline (188.610 us; speedup 1.0000x reference)
//
#include <hip/hip_runtime.h>
#include <hip/hip_bf16.h>

// Problem constants
#define Bc 2
#define Nc 6
#define Cc 128
#define Hc 16
#define Wc 44
#define Dc 64
#define HWc (Hc*Wc)          // 704
#define BNc (Bc*Nc)          // 12
#define NRAY (Nc*HWc)        // 4224 rays per batch
#define NPTS (Bc*Nc*Dc*HWc)  // 540672
#define BEV_W 256
#define BEV_H 256
#define BEV_HW (BEV_W*BEV_H) // 65536
#define NSEG (Bc*BEV_HW)     // 131072
#define GT 16                // cells per gather tile
#define NTILE (NSEG/GT)      // 8192 total (4096 per batch)

// ---------------- workspace layout (bytes) ----------------
#define OFF_KI   0                       // float Kinv[12][9]   (fallback path only)
#define OFF_DB   512                     // float dbins[64]     (fallback path only)
#define OFF_CNT  1024                    // int cnt[NSEG]      524288
#define OFF_OFFS (OFF_CNT  + 524288)     // int offs[NSEG]     524288 (scan1-block-local excl prefix)
#define OFF_FILL (OFF_OFFS + 524288)     // int fill[NSEG]     524288
#define OFF_BSUM (OFF_FILL + 524288)     // int bsum[256]      2048  (excl-scanned block sums)
#define OFF_E8   (OFF_BSUM + 2048)       // int2 e8[NPTS]      4325376 {ray|cell<<16, w-bits}
#define OFF_FT   (OFF_E8   + 4325376)    // float ft[B][NRAY][128] 4325376 (plain layout)
#define WS_NEED  (OFF_FT   + 4325376)    // ~9.8 MB
// fallback layout (round-2 proven path)
#define OFF_FIDX OFF_E8
#define OFF_FCNT OFF_CNT

// ---------------------------------------------------------------------------
// numpy-f32-exact setup of Kinv (per bn) and dbins.
// ---------------------------------------------------------------------------
__device__ __forceinline__ void setup_into(int tid, const float* __restrict__ intr,
                                           const int* __restrict__ p_imgh,
                                           const int* __restrict__ p_imgw,
                                           float* Ki, float* db) {
    if (tid < Dc) {
        double v = 1.0 + (double)tid * (59.0 / 63.0);
        db[tid] = (tid == Dc - 1) ? 60.0f : (float)v;   // np.linspace endpoint = stop
    }
    if (tid >= BNc) return;
    double img_h = (double)p_imgh[0];
    double img_w = (double)p_imgw[0];
    double scale_x = (double)Wc / (img_w / 16.0);
    double scale_y = (double)Hc / (img_h / 16.0);
    float rs0 = (float)(16.0 / scale_x);
    float rs1 = (float)(16.0 / scale_y);
    float rs2 = 1.0f;
    const float* K = intr + tid * 9;
    float k0 = __fmul_rn(K[0], rs0), k1 = __fmul_rn(K[1], rs0), k2 = __fmul_rn(K[2], rs0);
    float k3 = __fmul_rn(K[3], rs1), k4 = __fmul_rn(K[4], rs1), k5 = __fmul_rn(K[5], rs1);
    float k6 = __fmul_rn(K[6], rs2), k7 = __fmul_rn(K[7], rs2), k8 = __fmul_rn(K[8], rs2);
    float c0 = __fsub_rn(__fmul_rn(k4,k8), __fmul_rn(k5,k7));
    float c1 = __fsub_rn(__fmul_rn(k3,k8), __fmul_rn(k5,k6));
    float c2 = __fsub_rn(__fmul_rn(k3,k7), __fmul_rn(k4,k6));
    float det = __fadd_rn(__fsub_rn(__fmul_rn(k0,c0), __fmul_rn(k1,c1)), __fmul_rn(k2,c2));
    float* o = Ki + tid * 9;
    o[0] = __fdiv_rn(c0, det);
    o[1] = __fdiv_rn(__fsub_rn(__fmul_rn(k2,k7), __fmul_rn(k1,k8)), det);
    o[2] = __fdiv_rn(__fsub_rn(__fmul_rn(k1,k5), __fmul_rn(k2,k4)), det);
    o[3] = __fdiv_rn(__fsub_rn(__fmul_rn(k5,k6), __fmul_rn(k3,k8)), det);
    o[4] = __fdiv_rn(__fsub_rn(__fmul_rn(k0,k8), __fmul_rn(k2,k6)), det);
    o[5] = __fdiv_rn(__fsub_rn(__fmul_rn(k2,k3), __fmul_rn(k0,k5)), det);
    o[6] = __fdiv_rn(c2, det);
    o[7] = __fdiv_rn(__fsub_rn(__fmul_rn(k1,k6), __fmul_rn(k0,k7)), det);
    o[8] = __fdiv_rn(__fsub_rn(__fmul_rn(k0,k4), __fmul_rn(k1,k3)), det);
}

// fallback-path global setup kernel
__global__ void k_setup(const float* __restrict__ intr, const float* __restrict__ extr,
                        const int* __restrict__ p_imgh, const int* __restrict__ p_imgw,
                        float* __restrict__ Ki, float* __restrict__ db) {
    setup_into(threadIdx.x, intr, p_imgh, p_imgw, Ki, db);
}

// ---------------------------------------------------------------------------
// numpy-f32-exact classify: point gid -> BEV cell (or -1)
// ---------------------------------------------------------------------------
__device__ __forceinline__ int classify_point(int gid, const float* Ki_all,
                                              const float* db, const float* extr) {
    int p   = gid % HWc;
    int tmp = gid / HWc;
    int d   = tmp % Dc;
    int bn  = tmp / Dc;
    int w = p % Wc, h = p / Wc;
    float dd = db[d];
    float ud = __fmul_rn((float)w, dd);
    float vd = __fmul_rn((float)h, dd);
    const float* Ki = Ki_all + bn * 9;
    float pcx = fmaf(Ki[2], dd, fmaf(Ki[1], vd, __fmul_rn(Ki[0], ud)));
    float pcy = fmaf(Ki[5], dd, fmaf(Ki[4], vd, __fmul_rn(Ki[3], ud)));
    float pcz = fmaf(Ki[8], dd, fmaf(Ki[7], vd, __fmul_rn(Ki[6], ud)));
    const float* E = extr + bn * 16;
    float px = __fadd_rn(fmaf(E[2],  pcz, fmaf(E[1], pcy, __fmul_rn(E[0], pcx))), E[3]);
    float py = __fadd_rn(fmaf(E[6],  pcz, fmaf(E[5], pcy, __fmul_rn(E[4], pcx))), E[7]);
    float pz = __fadd_rn(fmaf(E[10], pcz, fmaf(E[9], pcy, __fmul_rn(E[8], pcx))), E[11]);
    float fx = __fdiv_rn(__fsub_rn(px, -51.2f), 0.4f);
    float fy = __fdiv_rn(__fsub_rn(py, -51.2f), 0.4f);
    int xi = (int)fx;
    int yi = (int)fy;
    bool valid = (xi >= 0) && (xi < BEV_W) && (yi >= 0) && (yi < BEV_H)
              && (pz >= -5.0f) && (pz <= 3.0f);
    return valid ? (yi * BEV_W + xi) : -1;
}

// ---------------------------------------------------------------------------
// Kernel A: count (+ fused setup in LDS, + fused transpose in first 528 blocks)
// transpose: feat [bn][c][hw] -> ft[b][ray][c] (plain channel order)
// ---------------------------------------------------------------------------
__global__ __launch_bounds__(256) void k_count(const float* __restrict__ intr,
                                               const float* __restrict__ extr,
                                               const int* __restrict__ p_imgh,
                                               const int* __restrict__ p_imgw,
                                               const float* __restrict__ feat,
                                               int* __restrict__ cntArr,
                                               float* __restrict__ ft) {
    __shared__ float sKi[BNc * 9];
    __shared__ float sDb[Dc];
    __shared__ float buf[Cc * 17];
    int tid = threadIdx.x;
    setup_into(tid, intr, p_imgh, p_imgw, sKi, sDb);
    __syncthreads();
    int gid = blockIdx.x * 256 + tid;      // grid = NPTS/256 exactly
    int cell = classify_point(gid, sKi, sDb, extr);
    if (cell >= 0) {
        int b = gid / (Nc * Dc * HWc);
        atomicAdd(&cntArr[b * BEV_HW + cell], 1);
    }
    // fused transpose: blocks [0, 528) each handle one 16-ray tile
    if (blockIdx.x < BNc * (HWc / 16)) {
        int bn   = blockIdx.x / (HWc / 16);
        int tile = blockIdx.x % (HWc / 16);
        const float* fb = feat + (size_t)bn * Cc * HWc + tile * 16;
        for (int i = tid; i < Cc * 16; i += 256) {
            int c = i >> 4, hw = i & 15;
            buf[c * 17 + hw] = fb[c * HWc + hw];
        }
        __syncthreads();
        float* obt = ft + ((size_t)bn * HWc + tile * 16) * Cc;
        for (int i = tid; i < 16 * Cc; i += 256) {
            int r = i >> 7, ch = i & 127;
            obt[(size_t)r * Cc + ch] = buf[ch * 17 + r];
        }
    }
}

// ---------------------------------------------------------------------------
// Scan: 512-thread block-local exclusive prefix (offs, fill) + 256 block
// sums; scan2 excl-scans them. Consumers add bsum[seg>>9] on the fly.
// ---------------------------------------------------------------------------
__global__ __launch_bounds__(512) void k_scan1(const int* __restrict__ cntArr,
                                               int* __restrict__ offs,
                                               int* __restrict__ fill,
                                               int* __restrict__ bsum) {
    __shared__ int s[512];
    int tid = threadIdx.x;
    int g = blockIdx.x * 512 + tid;
    int v = cntArr[g];
    s[tid] = v; __syncthreads();
    for (int st = 1; st < 512; st <<= 1) {
        int t = (tid >= st) ? s[tid - st] : 0;
        __syncthreads();
        s[tid] += t;
        __syncthreads();
    }
    int e = s[tid] - v;
    offs[g] = e;
    fill[g] = e;
    if (tid == 511) bsum[blockIdx.x] = s[511];
}

__global__ __launch_bounds__(256) void k_scan2(int* __restrict__ bsum) {
    __shared__ int s[256];
    int tid = threadIdx.x;
    int v = bsum[tid];
    s[tid] = v; __syncthreads();
    for (int st = 1; st < 256; st <<= 1) {
        int t = (tid >= st) ? s[tid - st] : 0;
        __syncthreads();
        s[tid] += t;
        __syncthreads();
    }
    bsum[tid] = s[tid] - v;   // exclusive
}

// ---------------------------------------------------------------------------
// Kernel B: fill packed entries {ray | cellLocal<<16, weight-bits}.
// ---------------------------------------------------------------------------
__global__ __launch_bounds__(256) void k_fill(const float* __restrict__ intr,
                                              const float* __restrict__ extr,
                                              const int* __restrict__ p_imgh,
                                              const int* __restrict__ p_imgw,
                                              const float* __restrict__ depth,
                                              int* __restrict__ fill,
                                              const int* __restrict__ bsum,
                                              int2* __restrict__ e8) {
    __shared__ float sKi[BNc * 9];
    __shared__ float sDb[Dc];
    int tid = threadIdx.x;
    setup_into(tid, intr, p_imgh, p_imgw, sKi, sDb);
    __syncthreads();
    int gid = blockIdx.x * 256 + tid;
    int cell = classify_point(gid, sKi, sDb, extr);
    if (cell < 0) return;
    int p  = gid % HWc;
    int bn = gid / (Dc * HWc);
    int b  = bn / Nc;
    int seg = b * BEV_HW + cell;
    int pos = atomicAdd(&fill[seg], 1) + bsum[seg >> 9];
    int ray = (bn % Nc) * HWc + p;
    e8[pos] = make_int2(ray | ((cell & (GT - 1)) << 16), __float_as_int(depth[gid]));
}

// ---------------------------------------------------------------------------
// Kernel C: gather v5. Same structure as v4 (wave-uniform entries, pure
// ds_write flush, 8-deep load pipeline) with three fixes:
//  (1) __launch_bounds__(256,4): LDS already caps at 4 blocks/CU = 16 waves,
//      so allow 128 VGPRs -> the 8-deep pipeline (e[8]+f[8]+en[8] ~ 48 regs)
//      is no longer register-serialized (round-7 showed VGPR_Count=52).
//  (2) wave-parallel shfl_up scan of the 16 cell counts (was tid0-serial).
//  (3) empty-tile fast path: E==0 -> stream zeros, skip LDS init/barriers.
// ---------------------------------------------------------------------------
#define RSTRIDE 132              // floats per cell slot (132 mod 32 = 4)
#define RSZ (GT * RSTRIDE)       // 2112 floats per wave region
__global__ __launch_bounds__(256, 4) void k_gather(const float2* __restrict__ ft2,
                                                   const int2* __restrict__ e8,
                                                   const int* __restrict__ cntArr,
                                                   const int* __restrict__ offs,
                                                   const int* __restrict__ bsum,
                                                   float* __restrict__ out) {
    __shared__ float4 accv[RSZ];         // 4 regions * 2112 floats = 33792 B
    __shared__ float  sInv[GT];
    __shared__ int    sP[GT + 1];
    __shared__ int    sO[1];
    float* accf = (float*)accv;

    int idx = blockIdx.x;
    int b   = idx >> 12;                 // 4096 tiles per batch
    int t   = idx & 4095;
    int ri  = t >> 4, ci = t & 15;       // ri in [0,256), ci in [0,16)
    int row = (ri & 1) ? (127 - (ri >> 1)) : (128 + (ri >> 1));   // center-first
    int col = (ci & 1) ? (7  - (ci >> 1)) : (8  + (ci >> 1));
    int cell0 = row * BEV_W + col * GT;
    int seg0  = b * BEV_HW + cell0;
    int tid = threadIdx.x;

    // wave 0: load 16 counts, 16-lane inclusive shfl scan
    if (tid < 64) {
        int n = (tid < GT) ? cntArr[seg0 + tid] : 0;
        int v = n;
        #pragma unroll
        for (int d = 1; d < GT; d <<= 1) {
            int y = __shfl_up(v, d, GT);
            if ((tid & (GT - 1)) >= d) v += y;
        }
        if (tid < GT) {
            sP[tid + 1] = v;
            sInv[tid] = __fdiv_rn(1.0f, __fadd_rn((float)n, 1e-5f));
        }
        if (tid == 0) {
            sP[0] = 0;
            sO[0] = offs[seg0] + bsum[seg0 >> 9];
        }
    }
    __syncthreads();
    int E  = sP[GT];
    int o0 = sO[0];

    float* ob = out + (size_t)b * Cc * BEV_HW + cell0;
    if (E == 0) {                        // empty tile: stream zeros, done
        float4 z = {0.f, 0.f, 0.f, 0.f};
        for (int i = tid; i < Cc * GT / 4; i += 256) {
            int q = i & 3, c = i >> 2;
            *(float4*)(ob + (size_t)c * BEV_HW + q * 4) = z;
        }
        return;
    }

    for (int i = tid; i < RSZ; i += 256) accv[i] = make_float4(0.f, 0.f, 0.f, 0.f);
    __syncthreads();

    int w = tid >> 6, lane = tid & 63;
    float* accw = accf + w * RSZ;
    if (E > w) {
        const float2* ftb = ft2 + (size_t)b * (NRAY * 64);
        int nt = (E - w + 3) >> 2;       // entries for this wave (k = w + 4*t)
        const int U = 8;
        int ngr = nt / U;
        float2 a = make_float2(0.f, 0.f);
        int curc = -1;
        if (ngr > 0) {
            int2 e[U];
            #pragma unroll
            for (int u = 0; u < U; u++) e[u] = e8[o0 + w + 4 * u];
            for (int g = 0; g < ngr; g++) {
                float2 f[U];
                #pragma unroll
                for (int u = 0; u < U; u++)
                    f[u] = ftb[(size_t)(e[u].x & 0xFFFF) * 64 + lane];
                int2 en[U];
                if (g + 1 < ngr) {
                    #pragma unroll
                    for (int u = 0; u < U; u++)
                        en[u] = e8[o0 + w + 4 * ((g + 1) * U + u)];
                } else {
                    #pragma unroll
                    for (int u = 0; u < U; u++) en[u] = e[u];
                }
                #pragma unroll
                for (int u = 0; u < U; u++) {
                    int c = e[u].x >> 16;                  // wave-uniform
                    if (c != curc) {
                        if (curc >= 0) *(float2*)(accw + curc * RSTRIDE + 2 * lane) = a;
                        curc = c; a.x = 0.f; a.y = 0.f;
                    }
                    float ww = __int_as_float(e[u].y);
                    a.x = fmaf(ww, f[u].x, a.x);
                    a.y = fmaf(ww, f[u].y, a.y);
                }
                #pragma unroll
                for (int u = 0; u < U; u++) e[u] = en[u];
            }
        }
        // batched tail (no serial dependent chain)
        int rem = nt - ngr * U;
        if (rem > 0) {
            int2 et[U];
            #pragma unroll
            for (int u = 0; u < U; u++)
                if (u < rem) et[u] = e8[o0 + w + 4 * (ngr * U + u)];
            float2 ftl[U];
            #pragma unroll
            for (int u = 0; u < U; u++)
                if (u < rem) ftl[u] = ftb[(size_t)(et[u].x & 0xFFFF) * 64 + lane];
            #pragma unroll
            for (int u = 0; u < U; u++)
                if (u < rem) {
                    int c = et[u].x >> 16;
                    if (c != curc) {
                        if (curc >= 0) *(float2*)(accw + curc * RSTRIDE + 2 * lane) = a;
                        curc = c; a.x = 0.f; a.y = 0.f;
                    }
                    float ww = __int_as_float(et[u].y);
                    a.x = fmaf(ww, ftl[u].x, a.x);
                    a.y = fmaf(ww, ftl[u].y, a.y);
                }
        }
        if (curc >= 0) *(float2*)(accw + curc * RSTRIDE + 2 * lane) = a;
    }
    __syncthreads();

    // epilogue: sum 4 regions, normalize, coalesced float4 stores
    for (int i = tid; i < Cc * GT / 4; i += 256) {   // 512 float4 stores
        int q = i & 3, c = i >> 2;
        float4 v;
        #pragma unroll
        for (int k = 0; k < 4; k++) {
            int g = q * 4 + k;
            int base = g * RSTRIDE + c;
            float s = __fadd_rn(__fadd_rn(accf[base], accf[RSZ + base]),
                                __fadd_rn(accf[2 * RSZ + base], accf[3 * RSZ + base]));
            (&v.x)[k] = __fmul_rn(s, sInv[g]);
        }
        *(float4*)(ob + (size_t)c * BEV_HW + q * 4) = v;
    }
}

// ======================= fallback (round-2 proven) ==========================
__global__ __launch_bounds__(256) void k_classifyF(const float* __restrict__ Ki_all,
                                                   const float* __restrict__ db,
                                                   const float* __restrict__ extr,
                                                   int* __restrict__ idxT,
                                                   float* __restrict__ cnt) {
    int gid = blockIdx.x * 256 + threadIdx.x;
    if (gid >= NPTS) return;
    int cell = classify_point(gid, Ki_all, db, extr);
    idxT[gid] = cell;
    if (cell >= 0) {
        int b = gid / (Nc * Dc * HWc);
        atomicAdd(&cnt[b * BEV_HW + cell], 1.0f);
    }
}

__global__ __launch_bounds__(256) void k_scatterF(const float* __restrict__ feat,
                                                  const float* __restrict__ depth,
                                                  const int* __restrict__ idxT,
                                                  float* __restrict__ out) {
    __shared__ float s_dw[HWc];
    __shared__ int   s_idx[HWc];
    int blk = blockIdx.x;
    int bn  = blk / Dc;
    int b   = bn / Nc;
    int tid = threadIdx.x;
    const float* dp = depth + (size_t)blk * HWc;
    const int*   ip = idxT  + (size_t)blk * HWc;
    for (int p = tid; p < HWc; p += 256) { s_dw[p] = dp[p]; s_idx[p] = ip[p]; }
    __syncthreads();
    const float* fb = feat + (size_t)bn * Cc * HWc;
    float*       ob = out  + (size_t)b  * Cc * BEV_HW;
    for (int c = 0; c < Cc; c++) {
        const float* f = fb + (size_t)c * HWc;
        float*       o = ob + (size_t)c * BEV_HW;
        for (int p = tid; p < HWc; p += 256) {
            int cell = s_idx[p];
            if (cell >= 0) atomicAdd(&o[cell], __fmul_rn(f[p], s_dw[p]));
        }
    }
}

__global__ __launch_bounds__(256) void k_normF(float* __restrict__ out,
                                               const float* __restrict__ cnt) {
    int i = blockIdx.x * 256 + threadIdx.x;
    const int total = Bc * Cc * BEV_HW / 4;
    if (i >= total) return;
    int q = i % (BEV_HW / 4);
    int b = i / (Cc * BEV_HW / 4);
    float4 v = ((float4*)out)[i];
    float4 cv = ((const float4*)cnt)[b * (BEV_HW / 4) + q];
    v.x = __fdiv_rn(v.x, __fadd_rn(cv.x, 1e-5f));
    v.y = __fdiv_rn(v.y, __fadd_rn(cv.y, 1e-5f));
    v.z = __fdiv_rn(v.z, __fadd_rn(cv.z, 1e-5f));
    v.w = __fdiv_rn(v.w, __fadd_rn(cv.w, 1e-5f));
    ((float4*)out)[i] = v;
}

// ===========================================================================
extern "C" void kernel_launch(void* const* d_in, const int* in_sizes, int n_in,
                              void* d_out, int out_size, void* d_ws, size_t ws_size,
                              hipStream_t stream) {
    const float* feat  = (const float*)d_in[0];
    const float* depth = (const float*)d_in[1];
    const float* intr  = (const float*)d_in[2];
    const float* extr  = (const float*)d_in[3];
    const int*   imh   = (const int*)d_in[4];
    const int*   imw   = (const int*)d_in[5];
    float* out = (float*)d_out;
    char*  ws  = (char*)d_ws;

    if (ws_size >= (size_t)WS_NEED) {
        int*   cntA = (int*)(ws + OFF_CNT);
        int*   offs = (int*)(ws + OFF_OFFS);
        int*   fill = (int*)(ws + OFF_FILL);
        int*   bsum = (int*)(ws + OFF_BSUM);
        int2*  e8   = (int2*)(ws + OFF_E8);
        float* ft   = (float*)(ws + OFF_FT);

        hipMemsetAsync(cntA, 0, (size_t)NSEG * sizeof(int), stream);
        k_count<<<NPTS / 256, 256, 0, stream>>>(intr, extr, imh, imw, feat, cntA, ft);
        k_scan1<<<NSEG / 512, 512, 0, stream>>>(cntA, offs, fill, bsum);
        k_scan2<<<1, 256, 0, stream>>>(bsum);
        k_fill<<<NPTS / 256, 256, 0, stream>>>(intr, extr, imh, imw, depth, fill, bsum, e8);
        k_gather<<<NTILE, 256, 0, stream>>>((const float2*)ft, e8, cntA, offs, bsum, out);
    } else {
        float* Ki   = (float*)(ws + OFF_KI);
        float* db   = (float*)(ws + OFF_DB);
        int*   idxT = (int*)(ws + OFF_FIDX);
        float* cnt  = (float*)(ws + OFF_FCNT);
        hipMemsetAsync(out, 0, (size_t)out_size * sizeof(float), stream);
        hipMemsetAsync(cnt, 0, (size_t)Bc * BEV_HW * sizeof(float), stream);
        k_setup<<<1, 64, 0, stream>>>(intr, extr, imh, imw, Ki, db);
        k_classifyF<<<(NPTS + 255) / 256, 256, 0, stream>>>(Ki, db, extr, idxT, cnt);
        k_scatterF<<<Bc * Nc * Dc, 256, 0, stream>>>(feat, depth, idxT, out);
        k_normF<<<(Bc * Cc * BEV_HW / 4 + 255) / 256, 256, 0, stream>>>(out, cnt);
    }
}

// Round 9
// 174.667 us; speedup vs baseline: 1.0798x; 1.0798x over previous
//
#include <hip/hip_runtime.h>
#include <hip/hip_bf16.h>

// Problem constants
#define Bc 2
#define Nc 6
#define Cc 128
#define Hc 16
#define Wc 44
#define Dc 64
#define HWc (Hc*Wc)          // 704
#define BNc (Bc*Nc)          // 12
#define NRAY (Nc*HWc)        // 4224 rays per batch
#define NPTS (Bc*Nc*Dc*HWc)  // 540672
#define BEV_W 256
#define BEV_H 256
#define BEV_HW (BEV_W*BEV_H) // 65536
#define NSEG (Bc*BEV_HW)     // 131072
#define GT 16                // cells per tile (mid-tier gather + finish)
#define NTILE (NSEG/GT)      // 8192

// ---------------- workspace layout (bytes) ----------------
#define OFF_KI   0                       // float Kinv[12][9]   (fallback path only)
#define OFF_DB   512                     // float dbins[64]     (fallback path only)
#define OFF_CNT  1024                    // int cnt[NSEG]      524288
#define OFF_OFFS (OFF_CNT  + 524288)     // int offs[NSEG]     524288 (scan1-block-local excl prefix)
#define OFF_FILL (OFF_OFFS + 524288)     // int fill[NSEG]     524288
#define OFF_BSUM (OFF_FILL + 524288)     // int bsum[256]      1024
#define OFF_ETOT (OFF_BSUM + 1024)       // int Etot[1]
#define OFF_E8   (OFF_BSUM + 2048)       // int2 e8[NPTS]      4325376 {ray | seg<<13, w-bits}
#define OFF_FT   (OFF_E8   + 4325376)    // float ft[B][NRAY][128] 4325376 (plain layout)
#define WS_NEED  (OFF_FT   + 4325376)    // ~9.8 MB (mid tier)
#define OFF_ACC  (OFF_FT   + 4325376)    // float acc[NSEG][128] 67108864 (big tier only)
#define WS_BIG   (OFF_ACC  + 67108864)   // ~77 MB
// fallback layout (round-2 proven path)
#define OFF_FIDX OFF_E8
#define OFF_FCNT OFF_CNT

// ---------------------------------------------------------------------------
// numpy-f32-exact setup of Kinv (per bn) and dbins.
// ---------------------------------------------------------------------------
__device__ __forceinline__ void setup_into(int tid, const float* __restrict__ intr,
                                           const int* __restrict__ p_imgh,
                                           const int* __restrict__ p_imgw,
                                           float* Ki, float* db) {
    if (tid < Dc) {
        double v = 1.0 + (double)tid * (59.0 / 63.0);
        db[tid] = (tid == Dc - 1) ? 60.0f : (float)v;   // np.linspace endpoint = stop
    }
    if (tid >= BNc) return;
    double img_h = (double)p_imgh[0];
    double img_w = (double)p_imgw[0];
    double scale_x = (double)Wc / (img_w / 16.0);
    double scale_y = (double)Hc / (img_h / 16.0);
    float rs0 = (float)(16.0 / scale_x);
    float rs1 = (float)(16.0 / scale_y);
    float rs2 = 1.0f;
    const float* K = intr + tid * 9;
    float k0 = __fmul_rn(K[0], rs0), k1 = __fmul_rn(K[1], rs0), k2 = __fmul_rn(K[2], rs0);
    float k3 = __fmul_rn(K[3], rs1), k4 = __fmul_rn(K[4], rs1), k5 = __fmul_rn(K[5], rs1);
    float k6 = __fmul_rn(K[6], rs2), k7 = __fmul_rn(K[7], rs2), k8 = __fmul_rn(K[8], rs2);
    float c0 = __fsub_rn(__fmul_rn(k4,k8), __fmul_rn(k5,k7));
    float c1 = __fsub_rn(__fmul_rn(k3,k8), __fmul_rn(k5,k6));
    float c2 = __fsub_rn(__fmul_rn(k3,k7), __fmul_rn(k4,k6));
    float det = __fadd_rn(__fsub_rn(__fmul_rn(k0,c0), __fmul_rn(k1,c1)), __fmul_rn(k2,c2));
    float* o = Ki + tid * 9;
    o[0] = __fdiv_rn(c0, det);
    o[1] = __fdiv_rn(__fsub_rn(__fmul_rn(k2,k7), __fmul_rn(k1,k8)), det);
    o[2] = __fdiv_rn(__fsub_rn(__fmul_rn(k1,k5), __fmul_rn(k2,k4)), det);
    o[3] = __fdiv_rn(__fsub_rn(__fmul_rn(k5,k6), __fmul_rn(k3,k8)), det);
    o[4] = __fdiv_rn(__fsub_rn(__fmul_rn(k0,k8), __fmul_rn(k2,k6)), det);
    o[5] = __fdiv_rn(__fsub_rn(__fmul_rn(k2,k3), __fmul_rn(k0,k5)), det);
    o[6] = __fdiv_rn(c2, det);
    o[7] = __fdiv_rn(__fsub_rn(__fmul_rn(k1,k6), __fmul_rn(k0,k7)), det);
    o[8] = __fdiv_rn(__fsub_rn(__fmul_rn(k0,k4), __fmul_rn(k1,k3)), det);
}

// fallback-path global setup kernel
__global__ void k_setup(const float* __restrict__ intr, const float* __restrict__ extr,
                        const int* __restrict__ p_imgh, const int* __restrict__ p_imgw,
                        float* __restrict__ Ki, float* __restrict__ db) {
    setup_into(threadIdx.x, intr, p_imgh, p_imgw, Ki, db);
}

// ---------------------------------------------------------------------------
// numpy-f32-exact classify: point gid -> BEV cell (or -1)
// ---------------------------------------------------------------------------
__device__ __forceinline__ int classify_point(int gid, const float* Ki_all,
                                              const float* db, const float* extr) {
    int p   = gid % HWc;
    int tmp = gid / HWc;
    int d   = tmp % Dc;
    int bn  = tmp / Dc;
    int w = p % Wc, h = p / Wc;
    float dd = db[d];
    float ud = __fmul_rn((float)w, dd);
    float vd = __fmul_rn((float)h, dd);
    const float* Ki = Ki_all + bn * 9;
    float pcx = fmaf(Ki[2], dd, fmaf(Ki[1], vd, __fmul_rn(Ki[0], ud)));
    float pcy = fmaf(Ki[5], dd, fmaf(Ki[4], vd, __fmul_rn(Ki[3], ud)));
    float pcz = fmaf(Ki[8], dd, fmaf(Ki[7], vd, __fmul_rn(Ki[6], ud)));
    const float* E = extr + bn * 16;
    float px = __fadd_rn(fmaf(E[2],  pcz, fmaf(E[1], pcy, __fmul_rn(E[0], pcx))), E[3]);
    float py = __fadd_rn(fmaf(E[6],  pcz, fmaf(E[5], pcy, __fmul_rn(E[4], pcx))), E[7]);
    float pz = __fadd_rn(fmaf(E[10], pcz, fmaf(E[9], pcy, __fmul_rn(E[8], pcx))), E[11]);
    float fx = __fdiv_rn(__fsub_rn(px, -51.2f), 0.4f);
    float fy = __fdiv_rn(__fsub_rn(py, -51.2f), 0.4f);
    int xi = (int)fx;
    int yi = (int)fy;
    bool valid = (xi >= 0) && (xi < BEV_W) && (yi >= 0) && (yi < BEV_H)
              && (pz >= -5.0f) && (pz <= 3.0f);
    return valid ? (yi * BEV_W + xi) : -1;
}

// ---------------------------------------------------------------------------
// Kernel A: count (+ fused setup in LDS, + fused transpose in first 528 blocks)
// ---------------------------------------------------------------------------
__global__ __launch_bounds__(256) void k_count(const float* __restrict__ intr,
                                               const float* __restrict__ extr,
                                               const int* __restrict__ p_imgh,
                                               const int* __restrict__ p_imgw,
                                               const float* __restrict__ feat,
                                               int* __restrict__ cntArr,
                                               float* __restrict__ ft) {
    __shared__ float sKi[BNc * 9];
    __shared__ float sDb[Dc];
    __shared__ float buf[Cc * 17];
    int tid = threadIdx.x;
    setup_into(tid, intr, p_imgh, p_imgw, sKi, sDb);
    __syncthreads();
    int gid = blockIdx.x * 256 + tid;      // grid = NPTS/256 exactly
    int cell = classify_point(gid, sKi, sDb, extr);
    if (cell >= 0) {
        int b = gid / (Nc * Dc * HWc);
        atomicAdd(&cntArr[b * BEV_HW + cell], 1);
    }
    if (blockIdx.x < BNc * (HWc / 16)) {
        int bn   = blockIdx.x / (HWc / 16);
        int tile = blockIdx.x % (HWc / 16);
        const float* fb = feat + (size_t)bn * Cc * HWc + tile * 16;
        for (int i = tid; i < Cc * 16; i += 256) {
            int c = i >> 4, hw = i & 15;
            buf[c * 17 + hw] = fb[c * HWc + hw];
        }
        __syncthreads();
        float* obt = ft + ((size_t)bn * HWc + tile * 16) * Cc;
        for (int i = tid; i < 16 * Cc; i += 256) {
            int r = i >> 7, ch = i & 127;
            obt[(size_t)r * Cc + ch] = buf[ch * 17 + r];
        }
    }
}

// ---------------------------------------------------------------------------
// Scans (unchanged; scan2 additionally writes the grand total Etot)
// ---------------------------------------------------------------------------
__global__ __launch_bounds__(512) void k_scan1(const int* __restrict__ cntArr,
                                               int* __restrict__ offs,
                                               int* __restrict__ fill,
                                               int* __restrict__ bsum) {
    __shared__ int s[512];
    int tid = threadIdx.x;
    int g = blockIdx.x * 512 + tid;
    int v = cntArr[g];
    s[tid] = v; __syncthreads();
    for (int st = 1; st < 512; st <<= 1) {
        int t = (tid >= st) ? s[tid - st] : 0;
        __syncthreads();
        s[tid] += t;
        __syncthreads();
    }
    int e = s[tid] - v;
    offs[g] = e;
    fill[g] = e;
    if (tid == 511) bsum[blockIdx.x] = s[511];
}

__global__ __launch_bounds__(256) void k_scan2(int* __restrict__ bsum, int* __restrict__ pEtot) {
    __shared__ int s[256];
    int tid = threadIdx.x;
    int v = bsum[tid];
    s[tid] = v; __syncthreads();
    for (int st = 1; st < 256; st <<= 1) {
        int t = (tid >= st) ? s[tid - st] : 0;
        __syncthreads();
        s[tid] += t;
        __syncthreads();
    }
    if (tid == 255) pEtot[0] = s[255];   // total valid entries
    bsum[tid] = s[tid] - v;              // exclusive
}

// ---------------------------------------------------------------------------
// Kernel B: fill packed entries {ray | seg<<13, weight-bits}.
// ray < 4224 (13 bits), seg = b*65536+cell < 131072 (17 bits) -> 30 bits.
// ---------------------------------------------------------------------------
__global__ __launch_bounds__(256) void k_fill(const float* __restrict__ intr,
                                              const float* __restrict__ extr,
                                              const int* __restrict__ p_imgh,
                                              const int* __restrict__ p_imgw,
                                              const float* __restrict__ depth,
                                              int* __restrict__ fill,
                                              const int* __restrict__ bsum,
                                              int2* __restrict__ e8) {
    __shared__ float sKi[BNc * 9];
    __shared__ float sDb[Dc];
    int tid = threadIdx.x;
    setup_into(tid, intr, p_imgh, p_imgw, sKi, sDb);
    __syncthreads();
    int gid = blockIdx.x * 256 + tid;
    int cell = classify_point(gid, sKi, sDb, extr);
    if (cell < 0) return;
    int p  = gid % HWc;
    int bn = gid / (Dc * HWc);
    int b  = bn / Nc;
    int seg = b * BEV_HW + cell;
    int pos = atomicAdd(&fill[seg], 1) + bsum[seg >> 9];
    int ray = (bn % Nc) * HWc + p;
    e8[pos] = make_int2(ray | (seg << 13), __float_as_int(depth[gid]));
}

// ---------------------------------------------------------------------------
// BIG-TIER Kernel C1: gather v6 — entry-parallel with cell ownership.
// 2112 waves; wave owns entries [wid*256, +256) and processes every cell
// whose FIRST entry lies in its range (O(1) skip/extend via offs+cnt).
// Contiguous walk, flush-on-cell-change = one coalesced 512 B pure store to
// acc[seg][128]. No atomics, no LDS, no zero-init (exclusive ownership).
// 8-deep load pipeline (proven v4 structure).
// ---------------------------------------------------------------------------
__global__ __launch_bounds__(256) void k_gather2(const float2* __restrict__ ft2,
                                                 const int2* __restrict__ e8,
                                                 const int* __restrict__ cntArr,
                                                 const int* __restrict__ offs,
                                                 const int* __restrict__ bsum,
                                                 const int* __restrict__ pEtot,
                                                 float* __restrict__ acc) {
    const int WCH = 256;
    int wid  = blockIdx.x * 4 + (threadIdx.x >> 6);
    int lane = threadIdx.x & 63;
    int Etot = pEtot[0];
    int start = wid * WCH;
    if (start >= Etot) return;
    int end = start + WCH; if (end > Etot) end = Etot;
    int k0 = 0;
    if (start > 0) {
        int segP = e8[start - 1].x >> 13;
        k0 = offs[segP] + bsum[segP >> 9] + cntArr[segP];  // end of segP's run
        if (k0 >= end) return;                             // no cell starts in range
    }
    int segE = e8[end - 1].x >> 13;
    int kend = offs[segE] + bsum[segE >> 9] + cntArr[segE];  // extend thru straddler
    int total = kend - k0;

    float2 a = make_float2(0.f, 0.f);
    int curc = -1;
    const int U = 8;
    int nb = total / U;
    if (nb > 0) {
        int2 e[U];
        #pragma unroll
        for (int u = 0; u < U; u++) e[u] = e8[k0 + u];
        for (int g = 0; g < nb; g++) {
            float2 f[U];
            #pragma unroll
            for (int u = 0; u < U; u++) {
                int sx = e[u].x;
                f[u] = ft2[((size_t)((sx >> 29) * NRAY) + (sx & 8191)) * 64 + lane];
            }
            int2 en[U];
            if (g + 1 < nb) {
                #pragma unroll
                for (int u = 0; u < U; u++) en[u] = e8[k0 + (g + 1) * U + u];
            } else {
                #pragma unroll
                for (int u = 0; u < U; u++) en[u] = e[u];
            }
            #pragma unroll
            for (int u = 0; u < U; u++) {
                int sg = e[u].x >> 13;
                if (sg != curc) {
                    if (curc >= 0) *(float2*)(acc + (size_t)curc * Cc + 2 * lane) = a;
                    curc = sg; a.x = 0.f; a.y = 0.f;
                }
                float ww = __int_as_float(e[u].y);
                a.x = fmaf(ww, f[u].x, a.x);
                a.y = fmaf(ww, f[u].y, a.y);
            }
            #pragma unroll
            for (int u = 0; u < U; u++) e[u] = en[u];
        }
    }
    for (int j = nb * U; j < total; j++) {     // tail <= 7
        int2 ee = e8[k0 + j];
        int sg = ee.x >> 13;
        if (sg != curc) {
            if (curc >= 0) *(float2*)(acc + (size_t)curc * Cc + 2 * lane) = a;
            curc = sg; a.x = 0.f; a.y = 0.f;
        }
        float ww = __int_as_float(ee.y);
        float2 f = ft2[((size_t)((ee.x >> 29) * NRAY) + (ee.x & 8191)) * 64 + lane];
        a.x = fmaf(ww, f.x, a.x);
        a.y = fmaf(ww, f.y, a.y);
    }
    if (curc >= 0) *(float2*)(acc + (size_t)curc * Cc + 2 * lane) = a;
}

// ---------------------------------------------------------------------------
// BIG-TIER Kernel C2: finish — normalize + transpose acc[seg][c] -> out[b][c][cell].
// Block = 16 consecutive cells. Empty group fast path. acc rows read as
// coalesced float4; epilogue = v5's proven store mapping (full 64 B lines).
// ---------------------------------------------------------------------------
__global__ __launch_bounds__(256) void k_finish(const float* __restrict__ acc,
                                                const int* __restrict__ cntArr,
                                                float* __restrict__ out) {
    __shared__ float res[GT * 132];
    __shared__ float sInv[GT];
    __shared__ int   sC[GT + 1];
    int seg0  = blockIdx.x * GT;
    int b     = seg0 >> 16;
    int cell0 = seg0 & 65535;
    int tid = threadIdx.x;
    if (tid < 64) {
        int n = (tid < GT) ? cntArr[seg0 + tid] : 0;
        int v = n;
        #pragma unroll
        for (int d = 1; d < GT; d <<= 1) {
            int y = __shfl_up(v, d, GT);
            if ((tid & (GT - 1)) >= d) v += y;
        }
        if (tid < GT) {
            sC[tid] = n;
            sInv[tid] = __fdiv_rn(1.0f, __fadd_rn((float)n, 1e-5f));
            if (tid == GT - 1) sC[GT] = v;
        }
    }
    __syncthreads();
    float* ob = out + (size_t)b * Cc * BEV_HW + cell0;
    if (sC[GT] == 0) {                       // all 16 cells empty
        float4 z = {0.f, 0.f, 0.f, 0.f};
        for (int i = tid; i < Cc * GT / 4; i += 256) {
            int q = i & 3, c = i >> 2;
            *(float4*)(ob + (size_t)c * BEV_HW + q * 4) = z;
        }
        return;
    }
    {
        int g0 = tid >> 5, l32 = tid & 31;
        #pragma unroll
        for (int pass = 0; pass < 2; pass++) {
            int g = g0 + pass * 8;
            float4 v;
            if (sC[g] > 0) v = *(const float4*)(acc + (size_t)(seg0 + g) * Cc + 4 * l32);
            else           v = make_float4(0.f, 0.f, 0.f, 0.f);
            *(float4*)(&res[g * 132 + 4 * l32]) = v;
        }
    }
    __syncthreads();
    for (int i = tid; i < Cc * GT / 4; i += 256) {
        int q = i & 3, c = i >> 2;
        float4 v;
        #pragma unroll
        for (int kk = 0; kk < 4; kk++) {
            int g = q * 4 + kk;
            (&v.x)[kk] = __fmul_rn(res[g * 132 + c], sInv[g]);
        }
        *(float4*)(ob + (size_t)c * BEV_HW + q * 4) = v;
    }
}

// ---------------------------------------------------------------------------
// MID-TIER Kernel: gather v5 (round-8 proven, 188 us total) — tile version.
// Only change: entry unpack matches the new e8 packing (ray=x&8191,
// cellLocal=(x>>13)&15).
// ---------------------------------------------------------------------------
#define RSTRIDE 132
#define RSZ (GT * RSTRIDE)
__global__ __launch_bounds__(256, 4) void k_gatherT(const float2* __restrict__ ft2,
                                                    const int2* __restrict__ e8,
                                                    const int* __restrict__ cntArr,
                                                    const int* __restrict__ offs,
                                                    const int* __restrict__ bsum,
                                                    float* __restrict__ out) {
    __shared__ float4 accv[RSZ];
    __shared__ float  sInv[GT];
    __shared__ int    sP[GT + 1];
    __shared__ int    sO[1];
    float* accf = (float*)accv;

    int idx = blockIdx.x;
    int b   = idx >> 12;
    int t   = idx & 4095;
    int ri  = t >> 4, ci = t & 15;
    int row = (ri & 1) ? (127 - (ri >> 1)) : (128 + (ri >> 1));
    int col = (ci & 1) ? (7  - (ci >> 1)) : (8  + (ci >> 1));
    int cell0 = row * BEV_W + col * GT;
    int seg0  = b * BEV_HW + cell0;
    int tid = threadIdx.x;

    if (tid < 64) {
        int n = (tid < GT) ? cntArr[seg0 + tid] : 0;
        int v = n;
        #pragma unroll
        for (int d = 1; d < GT; d <<= 1) {
            int y = __shfl_up(v, d, GT);
            if ((tid & (GT - 1)) >= d) v += y;
        }
        if (tid < GT) {
            sP[tid + 1] = v;
            sInv[tid] = __fdiv_rn(1.0f, __fadd_rn((float)n, 1e-5f));
        }
        if (tid == 0) {
            sP[0] = 0;
            sO[0] = offs[seg0] + bsum[seg0 >> 9];
        }
    }
    __syncthreads();
    int E  = sP[GT];
    int o0 = sO[0];

    float* ob = out + (size_t)b * Cc * BEV_HW + cell0;
    if (E == 0) {
        float4 z = {0.f, 0.f, 0.f, 0.f};
        for (int i = tid; i < Cc * GT / 4; i += 256) {
            int q = i & 3, c = i >> 2;
            *(float4*)(ob + (size_t)c * BEV_HW + q * 4) = z;
        }
        return;
    }

    for (int i = tid; i < RSZ; i += 256) accv[i] = make_float4(0.f, 0.f, 0.f, 0.f);
    __syncthreads();

    int w = tid >> 6, lane = tid & 63;
    float* accw = accf + w * RSZ;
    if (E > w) {
        const float2* ftb = ft2 + (size_t)b * (NRAY * 64);
        int nt = (E - w + 3) >> 2;
        const int U = 8;
        int ngr = nt / U;
        float2 a = make_float2(0.f, 0.f);
        int curc = -1;
        if (ngr > 0) {
            int2 e[U];
            #pragma unroll
            for (int u = 0; u < U; u++) e[u] = e8[o0 + w + 4 * u];
            for (int g = 0; g < ngr; g++) {
                float2 f[U];
                #pragma unroll
                for (int u = 0; u < U; u++)
                    f[u] = ftb[(size_t)(e[u].x & 8191) * 64 + lane];
                int2 en[U];
                if (g + 1 < ngr) {
                    #pragma unroll
                    for (int u = 0; u < U; u++)
                        en[u] = e8[o0 + w + 4 * ((g + 1) * U + u)];
                } else {
                    #pragma unroll
                    for (int u = 0; u < U; u++) en[u] = e[u];
                }
                #pragma unroll
                for (int u = 0; u < U; u++) {
                    int c = (e[u].x >> 13) & 15;
                    if (c != curc) {
                        if (curc >= 0) *(float2*)(accw + curc * RSTRIDE + 2 * lane) = a;
                        curc = c; a.x = 0.f; a.y = 0.f;
                    }
                    float ww = __int_as_float(e[u].y);
                    a.x = fmaf(ww, f[u].x, a.x);
                    a.y = fmaf(ww, f[u].y, a.y);
                }
                #pragma unroll
                for (int u = 0; u < U; u++) e[u] = en[u];
            }
        }
        int rem = nt - ngr * U;
        if (rem > 0) {
            int2 et[U];
            #pragma unroll
            for (int u = 0; u < U; u++)
                if (u < rem) et[u] = e8[o0 + w + 4 * (ngr * U + u)];
            float2 ftl[U];
            #pragma unroll
            for (int u = 0; u < U; u++)
                if (u < rem) ftl[u] = ftb[(size_t)(et[u].x & 8191) * 64 + lane];
            #pragma unroll
            for (int u = 0; u < U; u++)
                if (u < rem) {
                    int c = (et[u].x >> 13) & 15;
                    if (c != curc) {
                        if (curc >= 0) *(float2*)(accw + curc * RSTRIDE + 2 * lane) = a;
                        curc = c; a.x = 0.f; a.y = 0.f;
                    }
                    float ww = __int_as_float(et[u].y);
                    a.x = fmaf(ww, ftl[u].x, a.x);
                    a.y = fmaf(ww, ftl[u].y, a.y);
                }
        }
        if (curc >= 0) *(float2*)(accw + curc * RSTRIDE + 2 * lane) = a;
    }
    __syncthreads();

    for (int i = tid; i < Cc * GT / 4; i += 256) {
        int q = i & 3, c = i >> 2;
        float4 v;
        #pragma unroll
        for (int k = 0; k < 4; k++) {
            int g = q * 4 + k;
            int base = g * RSTRIDE + c;
            float s = __fadd_rn(__fadd_rn(accf[base], accf[RSZ + base]),
                                __fadd_rn(accf[2 * RSZ + base], accf[3 * RSZ + base]));
            (&v.x)[k] = __fmul_rn(s, sInv[g]);
        }
        *(float4*)(ob + (size_t)c * BEV_HW + q * 4) = v;
    }
}

// ======================= fallback (round-2 proven) ==========================
__global__ __launch_bounds__(256) void k_classifyF(const float* __restrict__ Ki_all,
                                                   const float* __restrict__ db,
                                                   const float* __restrict__ extr,
                                                   int* __restrict__ idxT,
                                                   float* __restrict__ cnt) {
    int gid = blockIdx.x * 256 + threadIdx.x;
    if (gid >= NPTS) return;
    int cell = classify_point(gid, Ki_all, db, extr);
    idxT[gid] = cell;
    if (cell >= 0) {
        int b = gid / (Nc * Dc * HWc);
        atomicAdd(&cnt[b * BEV_HW + cell], 1.0f);
    }
}

__global__ __launch_bounds__(256) void k_scatterF(const float* __restrict__ feat,
                                                  const float* __restrict__ depth,
                                                  const int* __restrict__ idxT,
                                                  float* __restrict__ out) {
    __shared__ float s_dw[HWc];
    __shared__ int   s_idx[HWc];
    int blk = blockIdx.x;
    int bn  = blk / Dc;
    int b   = bn / Nc;
    int tid = threadIdx.x;
    const float* dp = depth + (size_t)blk * HWc;
    const int*   ip = idxT  + (size_t)blk * HWc;
    for (int p = tid; p < HWc; p += 256) { s_dw[p] = dp[p]; s_idx[p] = ip[p]; }
    __syncthreads();
    const float* fb = feat + (size_t)bn * Cc * HWc;
    float*       ob = out  + (size_t)b  * Cc * BEV_HW;
    for (int c = 0; c < Cc; c++) {
        const float* f = fb + (size_t)c * HWc;
        float*       o = ob + (size_t)c * BEV_HW;
        for (int p = tid; p < HWc; p += 256) {
            int cell = s_idx[p];
            if (cell >= 0) atomicAdd(&o[cell], __fmul_rn(f[p], s_dw[p]));
        }
    }
}

__global__ __launch_bounds__(256) void k_normF(float* __restrict__ out,
                                               const float* __restrict__ cnt) {
    int i = blockIdx.x * 256 + threadIdx.x;
    const int total = Bc * Cc * BEV_HW / 4;
    if (i >= total) return;
    int q = i % (BEV_HW / 4);
    int b = i / (Cc * BEV_HW / 4);
    float4 v = ((float4*)out)[i];
    float4 cv = ((const float4*)cnt)[b * (BEV_HW / 4) + q];
    v.x = __fdiv_rn(v.x, __fadd_rn(cv.x, 1e-5f));
    v.y = __fdiv_rn(v.y, __fadd_rn(cv.y, 1e-5f));
    v.z = __fdiv_rn(v.z, __fadd_rn(cv.z, 1e-5f));
    v.w = __fdiv_rn(v.w, __fadd_rn(cv.w, 1e-5f));
    ((float4*)out)[i] = v;
}

// ===========================================================================
extern "C" void kernel_launch(void* const* d_in, const int* in_sizes, int n_in,
                              void* d_out, int out_size, void* d_ws, size_t ws_size,
                              hipStream_t stream) {
    const float* feat  = (const float*)d_in[0];
    const float* depth = (const float*)d_in[1];
    const float* intr  = (const float*)d_in[2];
    const float* extr  = (const float*)d_in[3];
    const int*   imh   = (const int*)d_in[4];
    const int*   imw   = (const int*)d_in[5];
    float* out = (float*)d_out;
    char*  ws  = (char*)d_ws;

    if (ws_size >= (size_t)WS_NEED) {
        int*   cntA  = (int*)(ws + OFF_CNT);
        int*   offs  = (int*)(ws + OFF_OFFS);
        int*   fill  = (int*)(ws + OFF_FILL);
        int*   bsum  = (int*)(ws + OFF_BSUM);
        int*   pEtot = (int*)(ws + OFF_ETOT);
        int2*  e8    = (int2*)(ws + OFF_E8);
        float* ft    = (float*)(ws + OFF_FT);

        hipMemsetAsync(cntA, 0, (size_t)NSEG * sizeof(int), stream);
        k_count<<<NPTS / 256, 256, 0, stream>>>(intr, extr, imh, imw, feat, cntA, ft);
        k_scan1<<<NSEG / 512, 512, 0, stream>>>(cntA, offs, fill, bsum);
        k_scan2<<<1, 256, 0, stream>>>(bsum, pEtot);
        k_fill<<<NPTS / 256, 256, 0, stream>>>(intr, extr, imh, imw, depth, fill, bsum, e8);
        if (ws_size >= (size_t)WS_BIG) {
            float* acc = (float*)(ws + OFF_ACC);
            k_gather2<<<NPTS / 1024, 256, 0, stream>>>((const float2*)ft, e8, cntA,
                                                       offs, bsum, pEtot, acc);
            k_finish<<<NTILE, 256, 0, stream>>>(acc, cntA, out);
        } else {
            k_gatherT<<<NTILE, 256, 0, stream>>>((const float2*)ft, e8, cntA,
                                                 offs, bsum, out);
        }
    } else {
        float* Ki   = (float*)(ws + OFF_KI);
        float* db   = (float*)(ws + OFF_DB);
        int*   idxT = (int*)(ws + OFF_FIDX);
        float* cnt  = (float*)(ws + OFF_FCNT);
        hipMemsetAsync(out, 0, (size_t)out_size * sizeof(float), stream);
        hipMemsetAsync(cnt, 0, (size_t)Bc * BEV_HW * sizeof(float), stream);
        k_setup<<<1, 64, 0, stream>>>(intr, extr, imh, imw, Ki, db);
        k_classifyF<<<(NPTS + 255) / 256, 256, 0, stream>>>(Ki, db, extr, idxT, cnt);
        k_scatterF<<<Bc * Nc * Dc, 256, 0, stream>>>(feat, depth, idxT, out);
        k_normF<<<(Bc * Cc * BEV_HW / 4 + 255) / 256, 256, 0, stream>>>(out, cnt);
    }
}